// Round 10
// baseline (272.752 us; speedup 1.0000x reference)
//
#include <hip/hip_runtime.h>

typedef unsigned short ushort_t;
typedef unsigned int uint_t;
typedef __attribute__((ext_vector_type(8))) short bf16x8;
typedef __attribute__((ext_vector_type(4))) float f32x4;

__device__ inline ushort_t bf16_rne(float f) {
    uint_t u = __float_as_uint(f);
    return (ushort_t)((u + 0x7FFFu + ((u >> 16) & 1u)) >> 16);
}

__device__ inline uint_t pack2(float lo, float hi) {
    return (uint_t)bf16_rne(lo) | ((uint_t)bf16_rne(hi) << 16);
}

__device__ inline void acc8(uint4 v, float* a) {
    a[0] += __uint_as_float(v.x << 16);
    a[1] += __uint_as_float(v.x & 0xFFFF0000u);
    a[2] += __uint_as_float(v.y << 16);
    a[3] += __uint_as_float(v.y & 0xFFFF0000u);
    a[4] += __uint_as_float(v.z << 16);
    a[5] += __uint_as_float(v.z & 0xFFFF0000u);
    a[6] += __uint_as_float(v.w << 16);
    a[7] += __uint_as_float(v.w & 0xFFFF0000u);
}

__device__ inline void set8(uint4 v, float* a) {
    a[0] = __uint_as_float(v.x << 16);
    a[1] = __uint_as_float(v.x & 0xFFFF0000u);
    a[2] = __uint_as_float(v.y << 16);
    a[3] = __uint_as_float(v.y & 0xFFFF0000u);
    a[4] = __uint_as_float(v.z << 16);
    a[5] = __uint_as_float(v.z & 0xFFFF0000u);
    a[6] = __uint_as_float(v.w << 16);
    a[7] = __uint_as_float(v.w & 0xFFFF0000u);
}

__device__ inline float4 bf4_to_f4(uint2 v) {
    float4 f;
    f.x = __uint_as_float(v.x << 16);
    f.y = __uint_as_float(v.x & 0xFFFF0000u);
    f.z = __uint_as_float(v.y << 16);
    f.w = __uint_as_float(v.y & 0xFFFF0000u);
    return f;
}

// ============ bucketed CSR build (bucket = dst >> 8, <=512 buckets) ============

#define BSH 8
#define NBMAX 512
#define EPB 4096

__global__ __launch_bounds__(256) void k_bhist(const int* __restrict__ dst,
                                               int* __restrict__ bcnt, int E, int nb) {
    __shared__ int h[NBMAX];
    const int tid = threadIdx.x;
    for (int i = tid; i < NBMAX; i += 256) h[i] = 0;
    __syncthreads();
    const int e0 = blockIdx.x * EPB;
    for (int i = tid; i < EPB; i += 256) {
        int e = e0 + i;
        if (e < E) atomicAdd(&h[dst[e] >> BSH], 1);
    }
    __syncthreads();
    for (int i = tid; i < nb; i += 256)
        if (h[i]) atomicAdd(&bcnt[i], h[i]);
}

__global__ __launch_bounds__(512) void k_bscan(const int* __restrict__ bcnt,
                                               int* __restrict__ boff,
                                               int* __restrict__ bcur, int nb) {
    __shared__ int a[NBMAX];
    const int t = threadIdx.x;
    int v = (t < nb) ? bcnt[t] : 0;
    a[t] = v;
    __syncthreads();
    for (int off = 1; off < NBMAX; off <<= 1) {
        int x = (t >= off) ? a[t - off] : 0;
        __syncthreads();
        a[t] += x;
        __syncthreads();
    }
    if (t < nb) {
        int excl = a[t] - v;
        boff[t] = excl;
        bcur[t] = excl;
    }
}

__global__ __launch_bounds__(256) void k_bscatter(const int* __restrict__ src,
                                                  const int* __restrict__ dst,
                                                  int* __restrict__ bcur,
                                                  int2* __restrict__ pairs, int E, int nb) {
    __shared__ int h[NBMAX];
    __shared__ int base[NBMAX];
    const int tid = threadIdx.x;
    for (int i = tid; i < NBMAX; i += 256) h[i] = 0;
    __syncthreads();
    const int e0 = blockIdx.x * EPB;
    for (int i = tid; i < EPB; i += 256) {
        int e = e0 + i;
        if (e < E) atomicAdd(&h[dst[e] >> BSH], 1);
    }
    __syncthreads();
    for (int b = tid; b < nb; b += 256) {
        int c = h[b];
        base[b] = c ? atomicAdd(&bcur[b], c) : 0;
        h[b] = 0;
    }
    __syncthreads();
    for (int i = tid; i < EPB; i += 256) {
        int e = e0 + i;
        if (e < E) {
            int s = src[e], d = dst[e];
            int bk = d >> BSH;
            int off = atomicAdd(&h[bk], 1);
            pairs[base[bk] + off] = make_int2(s, d);
        }
    }
}

__global__ __launch_bounds__(256) void k_bcsr(const int2* __restrict__ pairs,
                                              const int* __restrict__ boff,
                                              const int* __restrict__ bcurEnd,
                                              int* __restrict__ rowptr,
                                              int* __restrict__ rowend,
                                              float* __restrict__ dinv,
                                              int* __restrict__ csr, int n) {
    __shared__ int deg[256], sc[256], cur[256];
    const int t = threadIdx.x;
    const int b = blockIdx.x;
    const int beg = boff[b], end = bcurEnd[b];
    deg[t] = 0;
    __syncthreads();
    for (int i = beg + t; i < end; i += 256) {
        int2 p = pairs[i];
        atomicAdd(&deg[p.y & 255], 1);
    }
    __syncthreads();
    int dv = deg[t];
    sc[t] = dv;
    __syncthreads();
    for (int off = 1; off < 256; off <<= 1) {
        int x = (t >= off) ? sc[t - off] : 0;
        __syncthreads();
        sc[t] += x;
        __syncthreads();
    }
    int excl = sc[t] - dv;
    cur[t] = excl;
    int d = (b << BSH) + t;
    if (d < n) {
        int r = beg + excl;
        rowptr[d] = r;
        rowend[d] = r + dv;
        dinv[d] = rsqrtf((float)dv + 1.0f);
    }
    __syncthreads();
    for (int i = beg + t; i < end; i += 256) {
        int2 p = pairs[i];
        int off = atomicAdd(&cur[p.y & 255], 1);
        csr[beg + off] = p.x;
    }
}

// --------- weight prep: Wt[c][k] = bf16(W[k][c]) for both layers ---------

__global__ __launch_bounds__(256) void k_prep_w(const float* __restrict__ W1,
                                                const float* __restrict__ W2,
                                                ushort_t* __restrict__ Wt1,
                                                ushort_t* __restrict__ Wt2) {
    int idx = blockIdx.x * 256 + threadIdx.x;
    if (idx < 16384) {
        int k = idx >> 7, c = idx & 127;
        Wt1[c * 128 + k] = bf16_rne(W1[idx]);
    } else if (idx < 24576) {
        int j = idx - 16384;
        int k = j >> 6, c = j & 63;
        Wt2[c * 128 + k] = bf16_rne(W2[j]);
    }
}

// --------- layer-1 MFMA GEMM, CHUNKED output: G1c[ch][i][0..16) , ch = c>>4 ---------

__global__ __launch_bounds__(256) void k_gemm1(const float* __restrict__ X,
                                               const ushort_t* __restrict__ Wt,
                                               const float* __restrict__ dinv,
                                               ushort_t* __restrict__ G, int n) {
    constexpr int KP = 136;
    __shared__ ushort_t Xs[128 * KP];
    __shared__ ushort_t Ws[128 * KP];

    const int tid = threadIdx.x;
    const int row0 = blockIdx.x * 128;
    const size_t n16 = (size_t)n * 16;

#pragma unroll
    for (int i = 0; i < 16; i++) {
        int idx = tid * 4 + i * 1024;
        int r = idx >> 7, k = idx & 127;
        int gr = row0 + r;
        float4 v = make_float4(0.f, 0.f, 0.f, 0.f);
        if (gr < n) v = *(const float4*)&X[(size_t)gr * 128 + k];
        ushort4 o;
        o.x = bf16_rne(v.x); o.y = bf16_rne(v.y);
        o.z = bf16_rne(v.z); o.w = bf16_rne(v.w);
        *(ushort4*)&Xs[r * KP + k] = o;
    }
#pragma unroll
    for (int i = 0; i < 8; i++) {
        int idx = tid * 8 + i * 2048;
        int r = idx >> 7, k = idx & 127;
        *(uint4*)&Ws[r * KP + k] = *(const uint4*)&Wt[idx];
    }
    __syncthreads();

    const int lane = tid & 63;
    const int wid = tid >> 6;
    const int wm = wid & 1, wn = wid >> 1;
    const int lr = lane & 15, kg = lane >> 4;

    f32x4 acc[4][4];
#pragma unroll
    for (int mi = 0; mi < 4; mi++)
#pragma unroll
        for (int ni = 0; ni < 4; ni++)
#pragma unroll
            for (int q = 0; q < 4; q++) acc[mi][ni][q] = 0.f;

    const ushort_t* xb = &Xs[(wm * 64 + lr) * KP + kg * 8];
    const ushort_t* wb = &Ws[(wn * 64 + lr) * KP + kg * 8];

#pragma unroll
    for (int ks = 0; ks < 4; ks++) {
        bf16x8 a[4], b[4];
#pragma unroll
        for (int mi = 0; mi < 4; mi++)
            a[mi] = *(const bf16x8*)&xb[mi * 16 * KP + ks * 32];
#pragma unroll
        for (int ni = 0; ni < 4; ni++)
            b[ni] = *(const bf16x8*)&wb[ni * 16 * KP + ks * 32];
#pragma unroll
        for (int mi = 0; mi < 4; mi++)
#pragma unroll
            for (int ni = 0; ni < 4; ni++)
                acc[mi][ni] = __builtin_amdgcn_mfma_f32_16x16x32_bf16(
                    a[mi], b[ni], acc[mi][ni], 0, 0, 0);
    }

#pragma unroll
    for (int mi = 0; mi < 4; mi++) {
        int r0 = row0 + wm * 64 + mi * 16 + kg * 4;
#pragma unroll
        for (int r = 0; r < 4; r++) {
            int gr = r0 + r;
            if (gr < n) {
                float s = dinv[gr];
#pragma unroll
                for (int ni = 0; ni < 4; ni++) {
                    int ch = wn * 4 + ni;
                    G[(size_t)ch * n16 + (size_t)gr * 16 + lr] =
                        bf16_rne(s * acc[mi][ni][r]);
                }
            }
        }
    }
}

// ---- layer-1 aggregation, CHUNKED: grid (nbx, 8); chunk slab (3.2 MB) L2-resident ----
// 2 lanes per row (uint4 = 8 bf16 each), 128 rows/block, 4-deep unroll.
// grid.x padded to multiple of 8 so row-block -> XCD mapping is chunk-invariant.

__global__ __launch_bounds__(256) void k_gather128c(const int* __restrict__ rowptr,
                                                    const int* __restrict__ rowend,
                                                    const int* __restrict__ csr,
                                                    const ushort_t* __restrict__ G1,
                                                    const float* __restrict__ dinv,
                                                    const float* __restrict__ b1,
                                                    ushort_t* __restrict__ H, int n) {
    const int ch = blockIdx.y;
    const int g = blockIdx.x * 128 + (threadIdx.x >> 1);
    const int off = (threadIdx.x & 1) * 8;
    if (g >= n) return;
    const size_t n16 = (size_t)n * 16;
    const ushort_t* Gc = G1 + (size_t)ch * n16;

    float a[8];
    set8(*(const uint4*)&Gc[(size_t)g * 16 + off], a);  // self-loop term
    int e = rowptr[g];
    const int end = rowend[g];
    for (; e + 3 < end; e += 4) {
        int s0 = csr[e], s1 = csr[e + 1], s2 = csr[e + 2], s3 = csr[e + 3];
        uint4 v0 = *(const uint4*)&Gc[(size_t)s0 * 16 + off];
        uint4 v1 = *(const uint4*)&Gc[(size_t)s1 * 16 + off];
        uint4 v2 = *(const uint4*)&Gc[(size_t)s2 * 16 + off];
        uint4 v3 = *(const uint4*)&Gc[(size_t)s3 * 16 + off];
        acc8(v0, a); acc8(v1, a); acc8(v2, a); acc8(v3, a);
    }
    for (; e < end; e++) {
        int s0 = csr[e];
        acc8(*(const uint4*)&Gc[(size_t)s0 * 16 + off], a);
    }
    const float di = dinv[g];
    float4 bb0 = *(const float4*)&b1[ch * 16 + off];
    float4 bb1 = *(const float4*)&b1[ch * 16 + off + 4];
    uint4 ov;
    ov.x = pack2(fmaxf(di * a[0] + bb0.x, 0.f), fmaxf(di * a[1] + bb0.y, 0.f));
    ov.y = pack2(fmaxf(di * a[2] + bb0.z, 0.f), fmaxf(di * a[3] + bb0.w, 0.f));
    ov.z = pack2(fmaxf(di * a[4] + bb1.x, 0.f), fmaxf(di * a[5] + bb1.y, 0.f));
    ov.w = pack2(fmaxf(di * a[6] + bb1.z, 0.f), fmaxf(di * a[7] + bb1.w, 0.f));
    *(uint4*)&H[(size_t)ch * n16 + (size_t)g * 16 + off] = ov;
}

// --------- layer-2 MFMA GEMM: reads CHUNKED H, writes linear G2 [n][64] ---------

__global__ __launch_bounds__(256) void k_gemm2(const ushort_t* __restrict__ H,
                                               const ushort_t* __restrict__ Wt,
                                               const float* __restrict__ dinv,
                                               ushort_t* __restrict__ G2, int n) {
    constexpr int KP = 136;
    __shared__ ushort_t Xs[128 * KP];
    __shared__ ushort_t Ws[64 * KP];

    const int tid = threadIdx.x;
    const int row0 = blockIdx.x * 128;
    const size_t n16 = (size_t)n * 16;

    // stage chunked H: u -> (chunk, row, half)
#pragma unroll
    for (int i = 0; i < 8; i++) {
        int u = tid + i * 256;          // [0, 2048)
        int ch = u >> 8;                // 8 chunks x 256 uint4
        int rr = (u & 255) >> 1;
        int hh = (u & 1) * 8;
        int gr = row0 + rr;
        uint4 v = make_uint4(0u, 0u, 0u, 0u);
        if (gr < n) v = *(const uint4*)&H[(size_t)ch * n16 + (size_t)gr * 16 + hh];
        *(uint4*)&Xs[rr * KP + ch * 16 + hh] = v;
    }
#pragma unroll
    for (int i = 0; i < 4; i++) {
        int idx = tid * 8 + i * 2048;
        int r = idx >> 7, k = idx & 127;
        *(uint4*)&Ws[r * KP + k] = *(const uint4*)&Wt[idx];
    }
    __syncthreads();

    const int lane = tid & 63;
    const int wid = tid >> 6;
    const int wm = wid & 1, wn = wid >> 1;
    const int lr = lane & 15, kg = lane >> 4;

    f32x4 acc[4][2];
#pragma unroll
    for (int mi = 0; mi < 4; mi++)
#pragma unroll
        for (int ni = 0; ni < 2; ni++)
#pragma unroll
            for (int q = 0; q < 4; q++) acc[mi][ni][q] = 0.f;

    const ushort_t* xb = &Xs[(wm * 64 + lr) * KP + kg * 8];
    const ushort_t* wb = &Ws[(wn * 32 + lr) * KP + kg * 8];

#pragma unroll
    for (int ks = 0; ks < 4; ks++) {
        bf16x8 a[4], b[2];
#pragma unroll
        for (int mi = 0; mi < 4; mi++)
            a[mi] = *(const bf16x8*)&xb[mi * 16 * KP + ks * 32];
#pragma unroll
        for (int ni = 0; ni < 2; ni++)
            b[ni] = *(const bf16x8*)&wb[ni * 16 * KP + ks * 32];
#pragma unroll
        for (int mi = 0; mi < 4; mi++)
#pragma unroll
            for (int ni = 0; ni < 2; ni++)
                acc[mi][ni] = __builtin_amdgcn_mfma_f32_16x16x32_bf16(
                    a[mi], b[ni], acc[mi][ni], 0, 0, 0);
    }

#pragma unroll
    for (int mi = 0; mi < 4; mi++) {
        int r0 = row0 + wm * 64 + mi * 16 + kg * 4;
#pragma unroll
        for (int r = 0; r < 4; r++) {
            int gr = r0 + r;
            if (gr < n) {
                float s = dinv[gr];
#pragma unroll
                for (int ni = 0; ni < 2; ni++) {
                    int c = wn * 32 + ni * 16 + lr;
                    G2[(size_t)gr * 64 + c] = bf16_rne(s * acc[mi][ni][r]);
                }
            }
        }
    }
}

// ---- layer-2 aggregation (bf16 G2 linear, 16 lanes/row, 8-deep) + mean-pool ----

__global__ __launch_bounds__(256) void k_gather64_pool(const int* __restrict__ rowptr,
                                                       const int* __restrict__ rowend,
                                                       const int* __restrict__ csr,
                                                       const ushort_t* __restrict__ G,
                                                       const float* __restrict__ dinv,
                                                       const float* __restrict__ b,
                                                       const int* __restrict__ batch,
                                                       float* __restrict__ pool, int n) {
    __shared__ float po[16][68];
    __shared__ int pg[16];
    const int grp = threadIdx.x / 16;
    const int lane = threadIdx.x & 15;
    const int g = blockIdx.x * 16 + grp;

    float4 o = make_float4(0.f, 0.f, 0.f, 0.f);
    if (g < n) {
        const int beg = rowptr[g], end = rowend[g];
        float4 acc = bf4_to_f4(*(const uint2*)&G[(size_t)g * 64 + lane * 4]);
        int e = beg;
        for (; e + 7 < end; e += 8) {
            int s[8];
#pragma unroll
            for (int j = 0; j < 8; j++) s[j] = csr[e + j];
            uint2 rr[8];
#pragma unroll
            for (int j = 0; j < 8; j++)
                rr[j] = *(const uint2*)&G[(size_t)s[j] * 64 + lane * 4];
#pragma unroll
            for (int j = 0; j < 8; j++) {
                float4 a = bf4_to_f4(rr[j]);
                acc.x += a.x; acc.y += a.y; acc.z += a.z; acc.w += a.w;
            }
        }
        for (; e + 1 < end; e += 2) {
            int s0 = csr[e], s1 = csr[e + 1];
            uint2 r0 = *(const uint2*)&G[(size_t)s0 * 64 + lane * 4];
            uint2 r1 = *(const uint2*)&G[(size_t)s1 * 64 + lane * 4];
            float4 a0 = bf4_to_f4(r0), a1 = bf4_to_f4(r1);
            acc.x += a0.x + a1.x; acc.y += a0.y + a1.y;
            acc.z += a0.z + a1.z; acc.w += a0.w + a1.w;
        }
        if (e < end) {
            int s0 = csr[e];
            float4 a = bf4_to_f4(*(const uint2*)&G[(size_t)s0 * 64 + lane * 4]);
            acc.x += a.x; acc.y += a.y; acc.z += a.z; acc.w += a.w;
        }
        const float di = dinv[g];
        float4 bb = *(const float4*)&b[lane * 4];
        o.x = fmaxf(di * acc.x + bb.x, 0.f);
        o.y = fmaxf(di * acc.y + bb.y, 0.f);
        o.z = fmaxf(di * acc.z + bb.z, 0.f);
        o.w = fmaxf(di * acc.w + bb.w, 0.f);
    }
    if (lane == 0) pg[grp] = (g < n) ? batch[g] : -1;
    *(float4*)&po[grp][lane * 4] = o;
    __syncthreads();

    if (threadIdx.x < 64) {
        const int c = threadIdx.x;
        float run = 0.f;
        int cur = -1;
        for (int r = 0; r < 16; r++) {
            int gr = pg[r];
            if (gr < 0) continue;
            if (gr != cur) {
                if (cur >= 0) atomicAdd(&pool[cur * 64 + c], run);
                cur = gr;
                run = 0.f;
            }
            run += po[r][c];
        }
        if (cur >= 0) atomicAdd(&pool[cur * 64 + c], run);
    }
}

// -------------------- pooling tail --------------------

__global__ __launch_bounds__(64) void k_div_bs(const float* __restrict__ pool,
                                               const int* __restrict__ batch,
                                               float* __restrict__ out, int n) {
    int t = blockIdx.x * 64 + threadIdx.x;
    int g = t >> 6;
    int lo = 0, hi = n;
    while (lo < hi) { int m = (lo + hi) >> 1; if (batch[m] < g) lo = m + 1; else hi = m; }
    int lb = lo;
    lo = lb; hi = n;
    while (lo < hi) { int m = (lo + hi) >> 1; if (batch[m] <= g) lo = m + 1; else hi = m; }
    float c = (float)(lo - lb);
    c = c > 1.f ? c : 1.f;
    out[t] = pool[t] / c;
}

// -------------------- launch --------------------

extern "C" void kernel_launch(void* const* d_in, const int* in_sizes, int n_in,
                              void* d_out, int out_size, void* d_ws, size_t ws_size,
                              hipStream_t stream) {
    const float* x = (const float*)d_in[0];
    const int* edge = (const int*)d_in[1];
    const int* batch = (const int*)d_in[2];
    const float* W1 = (const float*)d_in[3];
    const float* b1 = (const float*)d_in[4];
    const float* W2 = (const float*)d_in[5];
    const float* b2 = (const float*)d_in[6];

    const int n = in_sizes[0] / 128;
    const int E = in_sizes[1] / 2;
    const int* src = edge;
    const int* dst = edge + E;
    const int nb = (n + 255) >> BSH;

    size_t nA = ((size_t)n + 255) & ~(size_t)255;
    float* dinv = (float*)d_ws;                      // nA
    int* rowptr = (int*)(dinv + nA);                 // nA
    int* rowend = rowptr + nA;                       // nA
    int* bcnt = rowend + nA;                         // 512
    int* boff = bcnt + NBMAX;                        // 512
    int* bcur = boff + NBMAX;                        // 512
    float* pool = (float*)(bcur + NBMAX);            // 4096 + 256 pad
    ushort_t* Wt1 = (ushort_t*)(pool + 4096 + 256);  // 16384 bf16
    ushort_t* Wt2 = Wt1 + 16384;                     // 8192 bf16
    ushort_t* bufG = Wt2 + 8192;                     // n*128 bf16, CHUNKED [8][n][16]
    ushort_t* bufH = bufG + (size_t)n * 128;         // n*128 bf16, CHUNKED [8][n][16]
    int* csr = (int*)(bufH + (size_t)n * 128);       // E
    int2* pairs = (int2*)bufG;                       // dead before gemm1

    hipMemsetAsync(bcnt, 0, NBMAX * 4, stream);
    hipMemsetAsync(pool, 0, 4096 * 4, stream);

    k_prep_w<<<96, 256, 0, stream>>>(W1, W2, Wt1, Wt2);

    // bucketed CSR build (+ dinv)
    int gE = (E + EPB - 1) / EPB;
    k_bhist<<<gE, 256, 0, stream>>>(dst, bcnt, E, nb);
    k_bscan<<<1, NBMAX, 0, stream>>>(bcnt, boff, bcur, nb);
    k_bscatter<<<gE, 256, 0, stream>>>(src, dst, bcur, pairs, E, nb);
    k_bcsr<<<nb, 256, 0, stream>>>(pairs, boff, bcur, rowptr, rowend, dinv, csr, n);

    // layer 1: MFMA GEMM (f32 in -> chunked bf16 G1)
    k_gemm1<<<(n + 127) / 128, 256, 0, stream>>>(x, Wt1, dinv, bufG, n);

    // chunked gather: one slab (3.2 MB) per blockIdx.y pass, L2-resident per XCD
    int nbx = (((n + 127) / 128) + 7) & ~7;  // pad to multiple of 8: XCD-invariant rows
    k_gather128c<<<dim3(nbx, 8), 256, 0, stream>>>(rowptr, rowend, csr, bufG, dinv, b1,
                                                   bufH, n);

    // layer 2: MFMA GEMM (chunked bf16 H in -> linear bf16 G2)
    k_gemm2<<<(n + 127) / 128, 256, 0, stream>>>(bufH, Wt2, dinv, bufG, n);
    k_gather64_pool<<<(n + 15) / 16, 256, 0, stream>>>(rowptr, rowend, csr, bufG, dinv,
                                                       b2, batch, pool, n);

    k_div_bs<<<64, 64, 0, stream>>>(pool, batch, (float*)d_out, n);
}

// Round 11
// 244.626 us; speedup vs baseline: 1.1150x; 1.1150x over previous
//
#include <hip/hip_runtime.h>

typedef unsigned short ushort_t;
typedef unsigned int uint_t;
typedef __attribute__((ext_vector_type(8))) short bf16x8;
typedef __attribute__((ext_vector_type(4))) float f32x4;

__device__ inline ushort_t bf16_rne(float f) {
    uint_t u = __float_as_uint(f);
    return (ushort_t)((u + 0x7FFFu + ((u >> 16) & 1u)) >> 16);
}

__device__ inline uint_t pack2(float lo, float hi) {
    return (uint_t)bf16_rne(lo) | ((uint_t)bf16_rne(hi) << 16);
}

__device__ inline void acc8(uint4 v, float* a) {
    a[0] += __uint_as_float(v.x << 16);
    a[1] += __uint_as_float(v.x & 0xFFFF0000u);
    a[2] += __uint_as_float(v.y << 16);
    a[3] += __uint_as_float(v.y & 0xFFFF0000u);
    a[4] += __uint_as_float(v.z << 16);
    a[5] += __uint_as_float(v.z & 0xFFFF0000u);
    a[6] += __uint_as_float(v.w << 16);
    a[7] += __uint_as_float(v.w & 0xFFFF0000u);
}

__device__ inline void set8(uint4 v, float* a) {
    a[0] = __uint_as_float(v.x << 16);
    a[1] = __uint_as_float(v.x & 0xFFFF0000u);
    a[2] = __uint_as_float(v.y << 16);
    a[3] = __uint_as_float(v.y & 0xFFFF0000u);
    a[4] = __uint_as_float(v.z << 16);
    a[5] = __uint_as_float(v.z & 0xFFFF0000u);
    a[6] = __uint_as_float(v.w << 16);
    a[7] = __uint_as_float(v.w & 0xFFFF0000u);
}

__device__ inline float4 bf4_to_f4(uint2 v) {
    float4 f;
    f.x = __uint_as_float(v.x << 16);
    f.y = __uint_as_float(v.x & 0xFFFF0000u);
    f.z = __uint_as_float(v.y << 16);
    f.w = __uint_as_float(v.y & 0xFFFF0000u);
    return f;
}

// ============ bucketed CSR build (bucket = dst >> 8, <=512 buckets) ============

#define BSH 8
#define NBMAX 512
#define EPB 4096

__global__ __launch_bounds__(256) void k_bhist(const int* __restrict__ dst,
                                               int* __restrict__ bcnt, int E, int nb) {
    __shared__ int h[NBMAX];
    const int tid = threadIdx.x;
    for (int i = tid; i < NBMAX; i += 256) h[i] = 0;
    __syncthreads();
    const int e0 = blockIdx.x * EPB;
    for (int i = tid; i < EPB; i += 256) {
        int e = e0 + i;
        if (e < E) atomicAdd(&h[dst[e] >> BSH], 1);
    }
    __syncthreads();
    for (int i = tid; i < nb; i += 256)
        if (h[i]) atomicAdd(&bcnt[i], h[i]);
}

__global__ __launch_bounds__(512) void k_bscan(const int* __restrict__ bcnt,
                                               int* __restrict__ boff,
                                               int* __restrict__ bcur, int nb) {
    __shared__ int a[NBMAX];
    const int t = threadIdx.x;
    int v = (t < nb) ? bcnt[t] : 0;
    a[t] = v;
    __syncthreads();
    for (int off = 1; off < NBMAX; off <<= 1) {
        int x = (t >= off) ? a[t - off] : 0;
        __syncthreads();
        a[t] += x;
        __syncthreads();
    }
    if (t < nb) {
        int excl = a[t] - v;
        boff[t] = excl;
        bcur[t] = excl;
    }
}

__global__ __launch_bounds__(256) void k_bscatter(const int* __restrict__ src,
                                                  const int* __restrict__ dst,
                                                  int* __restrict__ bcur,
                                                  int2* __restrict__ pairs, int E, int nb) {
    __shared__ int h[NBMAX];
    __shared__ int base[NBMAX];
    const int tid = threadIdx.x;
    for (int i = tid; i < NBMAX; i += 256) h[i] = 0;
    __syncthreads();
    const int e0 = blockIdx.x * EPB;
    for (int i = tid; i < EPB; i += 256) {
        int e = e0 + i;
        if (e < E) atomicAdd(&h[dst[e] >> BSH], 1);
    }
    __syncthreads();
    for (int b = tid; b < nb; b += 256) {
        int c = h[b];
        base[b] = c ? atomicAdd(&bcur[b], c) : 0;
        h[b] = 0;
    }
    __syncthreads();
    for (int i = tid; i < EPB; i += 256) {
        int e = e0 + i;
        if (e < E) {
            int s = src[e], d = dst[e];
            int bk = d >> BSH;
            int off = atomicAdd(&h[bk], 1);
            pairs[base[bk] + off] = make_int2(s, d);
        }
    }
}

__global__ __launch_bounds__(256) void k_bcsr(const int2* __restrict__ pairs,
                                              const int* __restrict__ boff,
                                              const int* __restrict__ bcurEnd,
                                              int* __restrict__ rowptr,
                                              int* __restrict__ rowend,
                                              float* __restrict__ dinv,
                                              int* __restrict__ csr, int n) {
    __shared__ int deg[256], sc[256], cur[256];
    const int t = threadIdx.x;
    const int b = blockIdx.x;
    const int beg = boff[b], end = bcurEnd[b];
    deg[t] = 0;
    __syncthreads();
    for (int i = beg + t; i < end; i += 256) {
        int2 p = pairs[i];
        atomicAdd(&deg[p.y & 255], 1);
    }
    __syncthreads();
    int dv = deg[t];
    sc[t] = dv;
    __syncthreads();
    for (int off = 1; off < 256; off <<= 1) {
        int x = (t >= off) ? sc[t - off] : 0;
        __syncthreads();
        sc[t] += x;
        __syncthreads();
    }
    int excl = sc[t] - dv;
    cur[t] = excl;
    int d = (b << BSH) + t;
    if (d < n) {
        int r = beg + excl;
        rowptr[d] = r;
        rowend[d] = r + dv;
        dinv[d] = rsqrtf((float)dv + 1.0f);
    }
    __syncthreads();
    for (int i = beg + t; i < end; i += 256) {
        int2 p = pairs[i];
        int off = atomicAdd(&cur[p.y & 255], 1);
        csr[beg + off] = p.x;
    }
}

// --------- weight prep: Wt[c][k] = bf16(W[k][c]) for both layers ---------

__global__ __launch_bounds__(256) void k_prep_w(const float* __restrict__ W1,
                                                const float* __restrict__ W2,
                                                ushort_t* __restrict__ Wt1,
                                                ushort_t* __restrict__ Wt2) {
    int idx = blockIdx.x * 256 + threadIdx.x;
    if (idx < 16384) {
        int k = idx >> 7, c = idx & 127;
        Wt1[c * 128 + k] = bf16_rne(W1[idx]);
    } else if (idx < 24576) {
        int j = idx - 16384;
        int k = j >> 6, c = j & 63;
        Wt2[c * 128 + k] = bf16_rne(W2[j]);
    }
}

// --------- layer-1 MFMA GEMM, CHUNKED output: G1c[ch][i][0..16) , ch = c>>4 ---------

__global__ __launch_bounds__(256) void k_gemm1(const float* __restrict__ X,
                                               const ushort_t* __restrict__ Wt,
                                               const float* __restrict__ dinv,
                                               ushort_t* __restrict__ G, int n) {
    constexpr int KP = 136;
    __shared__ ushort_t Xs[128 * KP];
    __shared__ ushort_t Ws[128 * KP];

    const int tid = threadIdx.x;
    const int row0 = blockIdx.x * 128;
    const size_t n16 = (size_t)n * 16;

#pragma unroll
    for (int i = 0; i < 16; i++) {
        int idx = tid * 4 + i * 1024;
        int r = idx >> 7, k = idx & 127;
        int gr = row0 + r;
        float4 v = make_float4(0.f, 0.f, 0.f, 0.f);
        if (gr < n) v = *(const float4*)&X[(size_t)gr * 128 + k];
        ushort4 o;
        o.x = bf16_rne(v.x); o.y = bf16_rne(v.y);
        o.z = bf16_rne(v.z); o.w = bf16_rne(v.w);
        *(ushort4*)&Xs[r * KP + k] = o;
    }
#pragma unroll
    for (int i = 0; i < 8; i++) {
        int idx = tid * 8 + i * 2048;
        int r = idx >> 7, k = idx & 127;
        *(uint4*)&Ws[r * KP + k] = *(const uint4*)&Wt[idx];
    }
    __syncthreads();

    const int lane = tid & 63;
    const int wid = tid >> 6;
    const int wm = wid & 1, wn = wid >> 1;
    const int lr = lane & 15, kg = lane >> 4;

    f32x4 acc[4][4];
#pragma unroll
    for (int mi = 0; mi < 4; mi++)
#pragma unroll
        for (int ni = 0; ni < 4; ni++)
#pragma unroll
            for (int q = 0; q < 4; q++) acc[mi][ni][q] = 0.f;

    const ushort_t* xb = &Xs[(wm * 64 + lr) * KP + kg * 8];
    const ushort_t* wb = &Ws[(wn * 64 + lr) * KP + kg * 8];

#pragma unroll
    for (int ks = 0; ks < 4; ks++) {
        bf16x8 a[4], b[4];
#pragma unroll
        for (int mi = 0; mi < 4; mi++)
            a[mi] = *(const bf16x8*)&xb[mi * 16 * KP + ks * 32];
#pragma unroll
        for (int ni = 0; ni < 4; ni++)
            b[ni] = *(const bf16x8*)&wb[ni * 16 * KP + ks * 32];
#pragma unroll
        for (int mi = 0; mi < 4; mi++)
#pragma unroll
            for (int ni = 0; ni < 4; ni++)
                acc[mi][ni] = __builtin_amdgcn_mfma_f32_16x16x32_bf16(
                    a[mi], b[ni], acc[mi][ni], 0, 0, 0);
    }

#pragma unroll
    for (int mi = 0; mi < 4; mi++) {
        int r0 = row0 + wm * 64 + mi * 16 + kg * 4;
#pragma unroll
        for (int r = 0; r < 4; r++) {
            int gr = r0 + r;
            if (gr < n) {
                float s = dinv[gr];
#pragma unroll
                for (int ni = 0; ni < 4; ni++) {
                    int ch = wn * 4 + ni;
                    G[(size_t)ch * n16 + (size_t)gr * 16 + lr] =
                        bf16_rne(s * acc[mi][ni][r]);
                }
            }
        }
    }
}

// ---- layer-1 aggregation, chunk = blockIdx.x & 7 -> one 3.2 MB slab per XCD ----
// (round-robin bid->XCD assumed: each XCD keeps its slab L2-resident)

__global__ __launch_bounds__(256) void k_gather128c(const int* __restrict__ rowptr,
                                                    const int* __restrict__ rowend,
                                                    const int* __restrict__ csr,
                                                    const ushort_t* __restrict__ G1,
                                                    const float* __restrict__ dinv,
                                                    const float* __restrict__ b1,
                                                    ushort_t* __restrict__ H, int n) {
    const int ch = blockIdx.x & 7;
    const int g = (blockIdx.x >> 3) * 128 + (threadIdx.x >> 1);
    const int off = (threadIdx.x & 1) * 8;
    if (g >= n) return;
    const size_t n16 = (size_t)n * 16;
    const ushort_t* Gc = G1 + (size_t)ch * n16;

    float a[8];
    set8(*(const uint4*)&Gc[(size_t)g * 16 + off], a);  // self-loop term
    int e = rowptr[g];
    const int end = rowend[g];
    for (; e + 3 < end; e += 4) {
        int s0 = csr[e], s1 = csr[e + 1], s2 = csr[e + 2], s3 = csr[e + 3];
        uint4 v0 = *(const uint4*)&Gc[(size_t)s0 * 16 + off];
        uint4 v1 = *(const uint4*)&Gc[(size_t)s1 * 16 + off];
        uint4 v2 = *(const uint4*)&Gc[(size_t)s2 * 16 + off];
        uint4 v3 = *(const uint4*)&Gc[(size_t)s3 * 16 + off];
        acc8(v0, a); acc8(v1, a); acc8(v2, a); acc8(v3, a);
    }
    for (; e < end; e++) {
        int s0 = csr[e];
        acc8(*(const uint4*)&Gc[(size_t)s0 * 16 + off], a);
    }
    const float di = dinv[g];
    float4 bb0 = *(const float4*)&b1[ch * 16 + off];
    float4 bb1 = *(const float4*)&b1[ch * 16 + off + 4];
    uint4 ov;
    ov.x = pack2(fmaxf(di * a[0] + bb0.x, 0.f), fmaxf(di * a[1] + bb0.y, 0.f));
    ov.y = pack2(fmaxf(di * a[2] + bb0.z, 0.f), fmaxf(di * a[3] + bb0.w, 0.f));
    ov.z = pack2(fmaxf(di * a[4] + bb1.x, 0.f), fmaxf(di * a[5] + bb1.y, 0.f));
    ov.w = pack2(fmaxf(di * a[6] + bb1.z, 0.f), fmaxf(di * a[7] + bb1.w, 0.f));
    *(uint4*)&H[(size_t)ch * n16 + (size_t)g * 16 + off] = ov;
}

// --------- layer-2 MFMA GEMM: reads CHUNKED H, writes linear G2 [n][64] ---------

__global__ __launch_bounds__(256) void k_gemm2(const ushort_t* __restrict__ H,
                                               const ushort_t* __restrict__ Wt,
                                               const float* __restrict__ dinv,
                                               ushort_t* __restrict__ G2, int n) {
    constexpr int KP = 136;
    __shared__ ushort_t Xs[128 * KP];
    __shared__ ushort_t Ws[64 * KP];

    const int tid = threadIdx.x;
    const int row0 = blockIdx.x * 128;
    const size_t n16 = (size_t)n * 16;

#pragma unroll
    for (int i = 0; i < 8; i++) {
        int u = tid + i * 256;
        int ch = u >> 8;
        int rr = (u & 255) >> 1;
        int hh = (u & 1) * 8;
        int gr = row0 + rr;
        uint4 v = make_uint4(0u, 0u, 0u, 0u);
        if (gr < n) v = *(const uint4*)&H[(size_t)ch * n16 + (size_t)gr * 16 + hh];
        *(uint4*)&Xs[rr * KP + ch * 16 + hh] = v;
    }
#pragma unroll
    for (int i = 0; i < 4; i++) {
        int idx = tid * 8 + i * 2048;
        int r = idx >> 7, k = idx & 127;
        *(uint4*)&Ws[r * KP + k] = *(const uint4*)&Wt[idx];
    }
    __syncthreads();

    const int lane = tid & 63;
    const int wid = tid >> 6;
    const int wm = wid & 1, wn = wid >> 1;
    const int lr = lane & 15, kg = lane >> 4;

    f32x4 acc[4][2];
#pragma unroll
    for (int mi = 0; mi < 4; mi++)
#pragma unroll
        for (int ni = 0; ni < 2; ni++)
#pragma unroll
            for (int q = 0; q < 4; q++) acc[mi][ni][q] = 0.f;

    const ushort_t* xb = &Xs[(wm * 64 + lr) * KP + kg * 8];
    const ushort_t* wb = &Ws[(wn * 32 + lr) * KP + kg * 8];

#pragma unroll
    for (int ks = 0; ks < 4; ks++) {
        bf16x8 a[4], b[2];
#pragma unroll
        for (int mi = 0; mi < 4; mi++)
            a[mi] = *(const bf16x8*)&xb[mi * 16 * KP + ks * 32];
#pragma unroll
        for (int ni = 0; ni < 2; ni++)
            b[ni] = *(const bf16x8*)&wb[ni * 16 * KP + ks * 32];
#pragma unroll
        for (int mi = 0; mi < 4; mi++)
#pragma unroll
            for (int ni = 0; ni < 2; ni++)
                acc[mi][ni] = __builtin_amdgcn_mfma_f32_16x16x32_bf16(
                    a[mi], b[ni], acc[mi][ni], 0, 0, 0);
    }

#pragma unroll
    for (int mi = 0; mi < 4; mi++) {
        int r0 = row0 + wm * 64 + mi * 16 + kg * 4;
#pragma unroll
        for (int r = 0; r < 4; r++) {
            int gr = r0 + r;
            if (gr < n) {
                float s = dinv[gr];
#pragma unroll
                for (int ni = 0; ni < 2; ni++) {
                    int c = wn * 32 + ni * 16 + lr;
                    G2[(size_t)gr * 64 + c] = bf16_rne(s * acc[mi][ni][r]);
                }
            }
        }
    }
}

// ---- layer-2 aggregation (bf16 G2 linear, 16 lanes/row, 8-deep) + mean-pool ----

__global__ __launch_bounds__(256) void k_gather64_pool(const int* __restrict__ rowptr,
                                                       const int* __restrict__ rowend,
                                                       const int* __restrict__ csr,
                                                       const ushort_t* __restrict__ G,
                                                       const float* __restrict__ dinv,
                                                       const float* __restrict__ b,
                                                       const int* __restrict__ batch,
                                                       float* __restrict__ pool, int n) {
    __shared__ float po[16][68];
    __shared__ int pg[16];
    const int grp = threadIdx.x / 16;
    const int lane = threadIdx.x & 15;
    const int g = blockIdx.x * 16 + grp;

    float4 o = make_float4(0.f, 0.f, 0.f, 0.f);
    if (g < n) {
        const int beg = rowptr[g], end = rowend[g];
        float4 acc = bf4_to_f4(*(const uint2*)&G[(size_t)g * 64 + lane * 4]);
        int e = beg;
        for (; e + 7 < end; e += 8) {
            int s[8];
#pragma unroll
            for (int j = 0; j < 8; j++) s[j] = csr[e + j];
            uint2 rr[8];
#pragma unroll
            for (int j = 0; j < 8; j++)
                rr[j] = *(const uint2*)&G[(size_t)s[j] * 64 + lane * 4];
#pragma unroll
            for (int j = 0; j < 8; j++) {
                float4 a = bf4_to_f4(rr[j]);
                acc.x += a.x; acc.y += a.y; acc.z += a.z; acc.w += a.w;
            }
        }
        for (; e + 1 < end; e += 2) {
            int s0 = csr[e], s1 = csr[e + 1];
            uint2 r0 = *(const uint2*)&G[(size_t)s0 * 64 + lane * 4];
            uint2 r1 = *(const uint2*)&G[(size_t)s1 * 64 + lane * 4];
            float4 a0 = bf4_to_f4(r0), a1 = bf4_to_f4(r1);
            acc.x += a0.x + a1.x; acc.y += a0.y + a1.y;
            acc.z += a0.z + a1.z; acc.w += a0.w + a1.w;
        }
        if (e < end) {
            int s0 = csr[e];
            float4 a = bf4_to_f4(*(const uint2*)&G[(size_t)s0 * 64 + lane * 4]);
            acc.x += a.x; acc.y += a.y; acc.z += a.z; acc.w += a.w;
        }
        const float di = dinv[g];
        float4 bb = *(const float4*)&b[lane * 4];
        o.x = fmaxf(di * acc.x + bb.x, 0.f);
        o.y = fmaxf(di * acc.y + bb.y, 0.f);
        o.z = fmaxf(di * acc.z + bb.z, 0.f);
        o.w = fmaxf(di * acc.w + bb.w, 0.f);
    }
    if (lane == 0) pg[grp] = (g < n) ? batch[g] : -1;
    *(float4*)&po[grp][lane * 4] = o;
    __syncthreads();

    if (threadIdx.x < 64) {
        const int c = threadIdx.x;
        float run = 0.f;
        int cur = -1;
        for (int r = 0; r < 16; r++) {
            int gr = pg[r];
            if (gr < 0) continue;
            if (gr != cur) {
                if (cur >= 0) atomicAdd(&pool[cur * 64 + c], run);
                cur = gr;
                run = 0.f;
            }
            run += po[r][c];
        }
        if (cur >= 0) atomicAdd(&pool[cur * 64 + c], run);
    }
}

// -------------------- pooling tail --------------------

__global__ __launch_bounds__(64) void k_div_bs(const float* __restrict__ pool,
                                               const int* __restrict__ batch,
                                               float* __restrict__ out, int n) {
    int t = blockIdx.x * 64 + threadIdx.x;
    int g = t >> 6;
    int lo = 0, hi = n;
    while (lo < hi) { int m = (lo + hi) >> 1; if (batch[m] < g) lo = m + 1; else hi = m; }
    int lb = lo;
    lo = lb; hi = n;
    while (lo < hi) { int m = (lo + hi) >> 1; if (batch[m] <= g) lo = m + 1; else hi = m; }
    float c = (float)(lo - lb);
    c = c > 1.f ? c : 1.f;
    out[t] = pool[t] / c;
}

// -------------------- launch --------------------

extern "C" void kernel_launch(void* const* d_in, const int* in_sizes, int n_in,
                              void* d_out, int out_size, void* d_ws, size_t ws_size,
                              hipStream_t stream) {
    const float* x = (const float*)d_in[0];
    const int* edge = (const int*)d_in[1];
    const int* batch = (const int*)d_in[2];
    const float* W1 = (const float*)d_in[3];
    const float* b1 = (const float*)d_in[4];
    const float* W2 = (const float*)d_in[5];
    const float* b2 = (const float*)d_in[6];

    const int n = in_sizes[0] / 128;
    const int E = in_sizes[1] / 2;
    const int* src = edge;
    const int* dst = edge + E;
    const int nb = (n + 255) >> BSH;

    size_t nA = ((size_t)n + 255) & ~(size_t)255;
    float* dinv = (float*)d_ws;                      // nA
    int* rowptr = (int*)(dinv + nA);                 // nA
    int* rowend = rowptr + nA;                       // nA
    int* bcnt = rowend + nA;                         // 512
    int* boff = bcnt + NBMAX;                        // 512
    int* bcur = boff + NBMAX;                        // 512
    float* pool = (float*)(bcur + NBMAX);            // 4096 + 256 pad
    ushort_t* Wt1 = (ushort_t*)(pool + 4096 + 256);  // 16384 bf16
    ushort_t* Wt2 = Wt1 + 16384;                     // 8192 bf16
    ushort_t* bufG = Wt2 + 8192;                     // n*128 bf16, CHUNKED [8][n][16]
    ushort_t* bufH = bufG + (size_t)n * 128;         // n*128 bf16, CHUNKED [8][n][16]
    int* csr = (int*)(bufH + (size_t)n * 128);       // E
    int2* pairs = (int2*)bufG;                       // dead before gemm1

    hipMemsetAsync(bcnt, 0, NBMAX * 4, stream);
    hipMemsetAsync(pool, 0, 4096 * 4, stream);

    k_prep_w<<<96, 256, 0, stream>>>(W1, W2, Wt1, Wt2);

    // bucketed CSR build (+ dinv)
    int gE = (E + EPB - 1) / EPB;
    k_bhist<<<gE, 256, 0, stream>>>(dst, bcnt, E, nb);
    k_bscan<<<1, NBMAX, 0, stream>>>(bcnt, boff, bcur, nb);
    k_bscatter<<<gE, 256, 0, stream>>>(src, dst, bcur, pairs, E, nb);
    k_bcsr<<<nb, 256, 0, stream>>>(pairs, boff, bcur, rowptr, rowend, dinv, csr, n);

    // layer 1: MFMA GEMM (f32 in -> chunked bf16 G1)
    k_gemm1<<<(n + 127) / 128, 256, 0, stream>>>(x, Wt1, dinv, bufG, n);

    // chunked gather, chunk = bid&7: one slab per XCD, L2-resident
    int nblk = ((n + 127) / 128) * 8;
    k_gather128c<<<nblk, 256, 0, stream>>>(rowptr, rowend, csr, bufG, dinv, b1,
                                           bufH, n);

    // layer 2: MFMA GEMM (chunked bf16 H in -> linear bf16 G2)
    k_gemm2<<<(n + 127) / 128, 256, 0, stream>>>(bufH, Wt2, dinv, bufG, n);
    k_gather64_pool<<<(n + 15) / 16, 256, 0, stream>>>(rowptr, rowend, csr, bufG, dinv,
                                                       b2, batch, pool, n);

    k_div_bs<<<64, 64, 0, stream>>>(pool, batch, (float*)d_out, n);
}

// Round 12
// 211.113 us; speedup vs baseline: 1.2920x; 1.1587x over previous
//
#include <hip/hip_runtime.h>

typedef unsigned short ushort_t;
typedef unsigned int uint_t;
typedef __attribute__((ext_vector_type(8))) short bf16x8;
typedef __attribute__((ext_vector_type(4))) float f32x4;

__device__ inline ushort_t bf16_rne(float f) {
    uint_t u = __float_as_uint(f);
    return (ushort_t)((u + 0x7FFFu + ((u >> 16) & 1u)) >> 16);
}

__device__ inline uint_t pack2(float lo, float hi) {
    return (uint_t)bf16_rne(lo) | ((uint_t)bf16_rne(hi) << 16);
}

__device__ inline void acc8(uint4 v, float* a) {
    a[0] += __uint_as_float(v.x << 16);
    a[1] += __uint_as_float(v.x & 0xFFFF0000u);
    a[2] += __uint_as_float(v.y << 16);
    a[3] += __uint_as_float(v.y & 0xFFFF0000u);
    a[4] += __uint_as_float(v.z << 16);
    a[5] += __uint_as_float(v.z & 0xFFFF0000u);
    a[6] += __uint_as_float(v.w << 16);
    a[7] += __uint_as_float(v.w & 0xFFFF0000u);
}

__device__ inline void set8(uint4 v, float* a) {
    a[0] = __uint_as_float(v.x << 16);
    a[1] = __uint_as_float(v.x & 0xFFFF0000u);
    a[2] = __uint_as_float(v.y << 16);
    a[3] = __uint_as_float(v.y & 0xFFFF0000u);
    a[4] = __uint_as_float(v.z << 16);
    a[5] = __uint_as_float(v.z & 0xFFFF0000u);
    a[6] = __uint_as_float(v.w << 16);
    a[7] = __uint_as_float(v.w & 0xFFFF0000u);
}

// ============ bucketed CSR build (bucket = dst >> 8; pairs packed in u32) ============
// pack: low 24 bits = src (n < 2^24), high 8 bits = dst & 255.

#define BSH 8
#define NBMAX 512
#define EPB 4096

__global__ __launch_bounds__(256) void k_bhist(const int* __restrict__ dst,
                                               int* __restrict__ bcnt, int E, int nb) {
    __shared__ int h[NBMAX];
    const int tid = threadIdx.x;
    for (int i = tid; i < NBMAX; i += 256) h[i] = 0;
    __syncthreads();
    const int e0 = blockIdx.x * EPB;
    for (int i = tid; i < EPB; i += 256) {
        int e = e0 + i;
        if (e < E) atomicAdd(&h[dst[e] >> BSH], 1);
    }
    __syncthreads();
    for (int i = tid; i < nb; i += 256)
        if (h[i]) atomicAdd(&bcnt[i], h[i]);
}

__global__ __launch_bounds__(512) void k_bscan(const int* __restrict__ bcnt,
                                               int* __restrict__ boff,
                                               int* __restrict__ bcur, int nb) {
    __shared__ int a[NBMAX];
    const int t = threadIdx.x;
    int v = (t < nb) ? bcnt[t] : 0;
    a[t] = v;
    __syncthreads();
    for (int off = 1; off < NBMAX; off <<= 1) {
        int x = (t >= off) ? a[t - off] : 0;
        __syncthreads();
        a[t] += x;
        __syncthreads();
    }
    if (t < nb) {
        int excl = a[t] - v;
        boff[t] = excl;
        bcur[t] = excl;
    }
}

__global__ __launch_bounds__(256) void k_bscatter(const int* __restrict__ src,
                                                  const int* __restrict__ dst,
                                                  int* __restrict__ bcur,
                                                  uint_t* __restrict__ pairs, int E, int nb) {
    __shared__ int h[NBMAX];
    __shared__ int base[NBMAX];
    const int tid = threadIdx.x;
    for (int i = tid; i < NBMAX; i += 256) h[i] = 0;
    __syncthreads();
    const int e0 = blockIdx.x * EPB;
    for (int i = tid; i < EPB; i += 256) {
        int e = e0 + i;
        if (e < E) atomicAdd(&h[dst[e] >> BSH], 1);
    }
    __syncthreads();
    for (int b = tid; b < nb; b += 256) {
        int c = h[b];
        base[b] = c ? atomicAdd(&bcur[b], c) : 0;
        h[b] = 0;
    }
    __syncthreads();
    for (int i = tid; i < EPB; i += 256) {
        int e = e0 + i;
        if (e < E) {
            int s = src[e], d = dst[e];
            int bk = d >> BSH;
            int off = atomicAdd(&h[bk], 1);
            pairs[base[bk] + off] = (uint_t)s | ((uint_t)(d & 255) << 24);
        }
    }
}

__global__ __launch_bounds__(256) void k_bcsr(const uint_t* __restrict__ pairs,
                                              const int* __restrict__ boff,
                                              const int* __restrict__ bcurEnd,
                                              int* __restrict__ rowptr,
                                              int* __restrict__ rowend,
                                              float* __restrict__ dinv,
                                              int* __restrict__ csr, int n) {
    __shared__ int deg[256], sc[256], cur[256];
    const int t = threadIdx.x;
    const int b = blockIdx.x;
    const int beg = boff[b], end = bcurEnd[b];
    deg[t] = 0;
    __syncthreads();
    for (int i = beg + t; i < end; i += 256) {
        uint_t p = pairs[i];
        atomicAdd(&deg[p >> 24], 1);
    }
    __syncthreads();
    int dv = deg[t];
    sc[t] = dv;
    __syncthreads();
    for (int off = 1; off < 256; off <<= 1) {
        int x = (t >= off) ? sc[t - off] : 0;
        __syncthreads();
        sc[t] += x;
        __syncthreads();
    }
    int excl = sc[t] - dv;
    cur[t] = excl;
    int d = (b << BSH) + t;
    if (d < n) {
        int r = beg + excl;
        rowptr[d] = r;
        rowend[d] = r + dv;
        dinv[d] = rsqrtf((float)dv + 1.0f);
    }
    __syncthreads();
    for (int i = beg + t; i < end; i += 256) {
        uint_t p = pairs[i];
        int off = atomicAdd(&cur[p >> 24], 1);
        csr[beg + off] = (int)(p & 0xFFFFFFu);
    }
}

// --------- weight prep: Wt[c][k] = bf16(W[k][c]) for both layers ---------

__global__ __launch_bounds__(256) void k_prep_w(const float* __restrict__ W1,
                                                const float* __restrict__ W2,
                                                ushort_t* __restrict__ Wt1,
                                                ushort_t* __restrict__ Wt2) {
    int idx = blockIdx.x * 256 + threadIdx.x;
    if (idx < 16384) {
        int k = idx >> 7, c = idx & 127;
        Wt1[c * 128 + k] = bf16_rne(W1[idx]);
    } else if (idx < 24576) {
        int j = idx - 16384;
        int k = j >> 6, c = j & 63;
        Wt2[c * 128 + k] = bf16_rne(W2[j]);
    }
}

// --------- MFMA GEMM: G[i][c] = bf16(dinv[i] * sum_k X[i][k]*W[k][c]) ---------

template <int DOUT, bool IN_BF16>
__global__ __launch_bounds__(256) void k_gemm_mfma(const void* __restrict__ Xv,
                                                   const ushort_t* __restrict__ Wt,
                                                   const float* __restrict__ dinv,
                                                   ushort_t* __restrict__ G, int n) {
    constexpr int KP = 136;
    constexpr int NW = DOUT / 2;
    constexpr int NT = NW / 16;
    __shared__ ushort_t Xs[128 * KP];
    __shared__ ushort_t Ws[DOUT * KP];

    const int tid = threadIdx.x;
    const int row0 = blockIdx.x * 128;

    if (!IN_BF16) {
        const float* X = (const float*)Xv;
#pragma unroll
        for (int i = 0; i < 16; i++) {
            int idx = tid * 4 + i * 1024;
            int r = idx >> 7, k = idx & 127;
            int gr = row0 + r;
            float4 v = make_float4(0.f, 0.f, 0.f, 0.f);
            if (gr < n) v = *(const float4*)&X[(size_t)gr * 128 + k];
            ushort4 o;
            o.x = bf16_rne(v.x); o.y = bf16_rne(v.y);
            o.z = bf16_rne(v.z); o.w = bf16_rne(v.w);
            *(ushort4*)&Xs[r * KP + k] = o;
        }
    } else {
        const ushort_t* X = (const ushort_t*)Xv;
#pragma unroll
        for (int i = 0; i < 8; i++) {
            int idx = tid * 8 + i * 2048;
            int r = idx >> 7, k = idx & 127;
            int gr = row0 + r;
            uint4 v = make_uint4(0u, 0u, 0u, 0u);
            if (gr < n) v = *(const uint4*)&X[(size_t)gr * 128 + k];
            *(uint4*)&Xs[r * KP + k] = v;
        }
    }
    constexpr int WI = (DOUT * 128) / 2048;
#pragma unroll
    for (int i = 0; i < WI; i++) {
        int idx = tid * 8 + i * 2048;
        int r = idx >> 7, k = idx & 127;
        *(uint4*)&Ws[r * KP + k] = *(const uint4*)&Wt[idx];
    }
    __syncthreads();

    const int lane = tid & 63;
    const int wid = tid >> 6;
    const int wm = wid & 1, wn = wid >> 1;
    const int lr = lane & 15, kg = lane >> 4;

    f32x4 acc[4][NT];
#pragma unroll
    for (int mi = 0; mi < 4; mi++)
#pragma unroll
        for (int ni = 0; ni < NT; ni++)
#pragma unroll
            for (int q = 0; q < 4; q++) acc[mi][ni][q] = 0.f;

    const ushort_t* xb = &Xs[(wm * 64 + lr) * KP + kg * 8];
    const ushort_t* wb = &Ws[(wn * NW + lr) * KP + kg * 8];

#pragma unroll
    for (int ks = 0; ks < 4; ks++) {
        bf16x8 a[4], b[NT];
#pragma unroll
        for (int mi = 0; mi < 4; mi++)
            a[mi] = *(const bf16x8*)&xb[mi * 16 * KP + ks * 32];
#pragma unroll
        for (int ni = 0; ni < NT; ni++)
            b[ni] = *(const bf16x8*)&wb[ni * 16 * KP + ks * 32];
#pragma unroll
        for (int mi = 0; mi < 4; mi++)
#pragma unroll
            for (int ni = 0; ni < NT; ni++)
                acc[mi][ni] = __builtin_amdgcn_mfma_f32_16x16x32_bf16(
                    a[mi], b[ni], acc[mi][ni], 0, 0, 0);
    }

#pragma unroll
    for (int mi = 0; mi < 4; mi++) {
        int r0 = row0 + wm * 64 + mi * 16 + kg * 4;
#pragma unroll
        for (int r = 0; r < 4; r++) {
            int gr = r0 + r;
            if (gr < n) {
                float s = dinv[gr];
#pragma unroll
                for (int ni = 0; ni < NT; ni++) {
                    int c = wn * NW + ni * 16 + lr;
                    G[(size_t)gr * DOUT + c] = bf16_rne(s * acc[mi][ni][r]);
                }
            }
        }
    }
}

// ---- layer-1 aggregation: 16 lanes/row x uint4, 8-deep unroll, bf16 H out ----

__global__ __launch_bounds__(256) void k_gather128(const int* __restrict__ rowptr,
                                                   const int* __restrict__ rowend,
                                                   const int* __restrict__ csr,
                                                   const ushort_t* __restrict__ G,
                                                   const float* __restrict__ dinv,
                                                   const float* __restrict__ b,
                                                   ushort_t* __restrict__ H, int n) {
    const int g = blockIdx.x * 16 + (threadIdx.x >> 4);
    const int lane = threadIdx.x & 15;
    const int koff = lane * 8;
    if (g >= n) return;
    const int beg = rowptr[g], end = rowend[g];

    float a[8];
    set8(*(const uint4*)&G[(size_t)g * 128 + koff], a);  // self term
    int e = beg;
    for (; e + 7 < end; e += 8) {
        int s[8];
#pragma unroll
        for (int j = 0; j < 8; j++) s[j] = csr[e + j];
        uint4 v[8];
#pragma unroll
        for (int j = 0; j < 8; j++)
            v[j] = *(const uint4*)&G[(size_t)s[j] * 128 + koff];
#pragma unroll
        for (int j = 0; j < 8; j++) acc8(v[j], a);
    }
    for (; e + 1 < end; e += 2) {
        int s0 = csr[e], s1 = csr[e + 1];
        uint4 v0 = *(const uint4*)&G[(size_t)s0 * 128 + koff];
        uint4 v1 = *(const uint4*)&G[(size_t)s1 * 128 + koff];
        acc8(v0, a); acc8(v1, a);
    }
    if (e < end) {
        int s0 = csr[e];
        acc8(*(const uint4*)&G[(size_t)s0 * 128 + koff], a);
    }
    const float di = dinv[g];
    float4 bb0 = *(const float4*)&b[koff];
    float4 bb1 = *(const float4*)&b[koff + 4];
    uint4 ov;
    ov.x = pack2(fmaxf(di * a[0] + bb0.x, 0.f), fmaxf(di * a[1] + bb0.y, 0.f));
    ov.y = pack2(fmaxf(di * a[2] + bb0.z, 0.f), fmaxf(di * a[3] + bb0.w, 0.f));
    ov.z = pack2(fmaxf(di * a[4] + bb1.x, 0.f), fmaxf(di * a[5] + bb1.y, 0.f));
    ov.w = pack2(fmaxf(di * a[6] + bb1.z, 0.f), fmaxf(di * a[7] + bb1.w, 0.f));
    *(uint4*)&H[(size_t)g * 128 + koff] = ov;
}

// ---- layer-2 aggregation: 8 lanes/row x uint4, 8-deep unroll + mean-pool ----

__global__ __launch_bounds__(256) void k_gather64_pool(const int* __restrict__ rowptr,
                                                       const int* __restrict__ rowend,
                                                       const int* __restrict__ csr,
                                                       const ushort_t* __restrict__ G,
                                                       const float* __restrict__ dinv,
                                                       const float* __restrict__ b,
                                                       const int* __restrict__ batch,
                                                       float* __restrict__ pool, int n) {
    __shared__ float po[32][72];
    __shared__ int pg[32];
    const int grp = threadIdx.x >> 3;
    const int lane = threadIdx.x & 7;
    const int g = blockIdx.x * 32 + grp;
    const int koff = lane * 8;

    float o8[8] = {0.f, 0.f, 0.f, 0.f, 0.f, 0.f, 0.f, 0.f};
    if (g < n) {
        float a[8];
        set8(*(const uint4*)&G[(size_t)g * 64 + koff], a);  // self term
        int e = rowptr[g];
        const int end = rowend[g];
        for (; e + 7 < end; e += 8) {
            int s[8];
#pragma unroll
            for (int j = 0; j < 8; j++) s[j] = csr[e + j];
            uint4 v[8];
#pragma unroll
            for (int j = 0; j < 8; j++)
                v[j] = *(const uint4*)&G[(size_t)s[j] * 64 + koff];
#pragma unroll
            for (int j = 0; j < 8; j++) acc8(v[j], a);
        }
        for (; e + 1 < end; e += 2) {
            int s0 = csr[e], s1 = csr[e + 1];
            uint4 v0 = *(const uint4*)&G[(size_t)s0 * 64 + koff];
            uint4 v1 = *(const uint4*)&G[(size_t)s1 * 64 + koff];
            acc8(v0, a); acc8(v1, a);
        }
        if (e < end) {
            int s0 = csr[e];
            acc8(*(const uint4*)&G[(size_t)s0 * 64 + koff], a);
        }
        const float di = dinv[g];
        float4 bb0 = *(const float4*)&b[koff];
        float4 bb1 = *(const float4*)&b[koff + 4];
        o8[0] = fmaxf(di * a[0] + bb0.x, 0.f);
        o8[1] = fmaxf(di * a[1] + bb0.y, 0.f);
        o8[2] = fmaxf(di * a[2] + bb0.z, 0.f);
        o8[3] = fmaxf(di * a[3] + bb0.w, 0.f);
        o8[4] = fmaxf(di * a[4] + bb1.x, 0.f);
        o8[5] = fmaxf(di * a[5] + bb1.y, 0.f);
        o8[6] = fmaxf(di * a[6] + bb1.z, 0.f);
        o8[7] = fmaxf(di * a[7] + bb1.w, 0.f);
    }
    if (lane == 0) pg[grp] = (g < n) ? batch[g] : -1;
    *(float4*)&po[grp][koff] = make_float4(o8[0], o8[1], o8[2], o8[3]);
    *(float4*)&po[grp][koff + 4] = make_float4(o8[4], o8[5], o8[6], o8[7]);
    __syncthreads();

    if (threadIdx.x < 64) {
        const int c = threadIdx.x;
        float run = 0.f;
        int cur = -1;
        for (int r = 0; r < 32; r++) {
            int gr = pg[r];
            if (gr < 0) continue;
            if (gr != cur) {
                if (cur >= 0) atomicAdd(&pool[cur * 64 + c], run);
                cur = gr;
                run = 0.f;
            }
            run += po[r][c];
        }
        if (cur >= 0) atomicAdd(&pool[cur * 64 + c], run);
    }
}

// -------------------- pooling tail --------------------

__global__ __launch_bounds__(64) void k_div_bs(const float* __restrict__ pool,
                                               const int* __restrict__ batch,
                                               float* __restrict__ out, int n) {
    int t = blockIdx.x * 64 + threadIdx.x;
    int g = t >> 6;
    int lo = 0, hi = n;
    while (lo < hi) { int m = (lo + hi) >> 1; if (batch[m] < g) lo = m + 1; else hi = m; }
    int lb = lo;
    lo = lb; hi = n;
    while (lo < hi) { int m = (lo + hi) >> 1; if (batch[m] <= g) lo = m + 1; else hi = m; }
    float c = (float)(lo - lb);
    c = c > 1.f ? c : 1.f;
    out[t] = pool[t] / c;
}

// -------------------- launch --------------------

extern "C" void kernel_launch(void* const* d_in, const int* in_sizes, int n_in,
                              void* d_out, int out_size, void* d_ws, size_t ws_size,
                              hipStream_t stream) {
    const float* x = (const float*)d_in[0];
    const int* edge = (const int*)d_in[1];
    const int* batch = (const int*)d_in[2];
    const float* W1 = (const float*)d_in[3];
    const float* b1 = (const float*)d_in[4];
    const float* W2 = (const float*)d_in[5];
    const float* b2 = (const float*)d_in[6];

    const int n = in_sizes[0] / 128;
    const int E = in_sizes[1] / 2;
    const int* src = edge;
    const int* dst = edge + E;
    const int nb = (n + 255) >> BSH;

    size_t nA = ((size_t)n + 255) & ~(size_t)255;
    float* dinv = (float*)d_ws;                      // nA
    int* rowptr = (int*)(dinv + nA);                 // nA
    int* rowend = rowptr + nA;                       // nA
    int* bcnt = rowend + nA;                         // 512
    int* boff = bcnt + NBMAX;                        // 512
    int* bcur = boff + NBMAX;                        // 512
    float* pool = (float*)(bcur + NBMAX);            // 4096 + 256 pad
    ushort_t* Wt1 = (ushort_t*)(pool + 4096 + 256);  // 16384 bf16
    ushort_t* Wt2 = Wt1 + 16384;                     // 8192 bf16
    ushort_t* bufG = Wt2 + 8192;                     // n*128 bf16 (pairs alias)
    ushort_t* bufH = bufG + (size_t)n * 128;         // n*128 bf16
    int* csr = (int*)(bufH + (size_t)n * 128);       // E
    uint_t* pairs = (uint_t*)bufG;                   // E u32, dead before gemm1

    hipMemsetAsync(bcnt, 0, NBMAX * 4, stream);
    hipMemsetAsync(pool, 0, 4096 * 4, stream);

    k_prep_w<<<96, 256, 0, stream>>>(W1, W2, Wt1, Wt2);

    // bucketed CSR build (+ dinv)
    int gE = (E + EPB - 1) / EPB;
    k_bhist<<<gE, 256, 0, stream>>>(dst, bcnt, E, nb);
    k_bscan<<<1, NBMAX, 0, stream>>>(bcnt, boff, bcur, nb);
    k_bscatter<<<gE, 256, 0, stream>>>(src, dst, bcur, pairs, E, nb);
    k_bcsr<<<nb, 256, 0, stream>>>(pairs, boff, bcur, rowptr, rowend, dinv, csr, n);

    // layer 1: MFMA GEMM (f32 in, bf16 out) -> gather (bf16 H out)
    k_gemm_mfma<128, false><<<(n + 127) / 128, 256, 0, stream>>>(x, Wt1, dinv, bufG, n);
    k_gather128<<<(n + 15) / 16, 256, 0, stream>>>(rowptr, rowend, csr, bufG, dinv, b1,
                                                   bufH, n);

    // layer 2: MFMA GEMM (bf16 in, bf16 out) -> gather + pool
    k_gemm_mfma<64, true><<<(n + 127) / 128, 256, 0, stream>>>(bufH, Wt2, dinv, bufG, n);
    k_gather64_pool<<<(n + 31) / 32, 256, 0, stream>>>(rowptr, rowend, csr, bufG, dinv,
                                                       b2, batch, pool, n);

    k_div_bs<<<64, 64, 0, stream>>>(pool, batch, (float*)d_out, n);
}